// Round 1
// baseline (67.989 us; speedup 1.0000x reference)
//
#include <hip/hip_runtime.h>

// out[b, e] = sum_d x[b, d] * T[g[b] % G, d, e]
// B=128, D=1024, G=40, all float32. g is integer (harness passes int32).

#define D_DIM 1024
#define B_DIM 128
#define G_DIM 40
#define COLS_PER_BLOCK 256
#define THREADS 256

__global__ __launch_bounds__(THREADS) void leqfc_matvec(
    const float* __restrict__ x,
    const int* __restrict__ g,
    const float* __restrict__ T,
    float* __restrict__ out)
{
    const int b   = blockIdx.x;                      // sample index 0..127
    const int c0  = blockIdx.y * COLS_PER_BLOCK;     // column chunk start
    const int tid = threadIdx.x;                     // 0..255
    const int col = c0 + tid;

    // Stage this sample's x-row (4 KB) in LDS; broadcast reads later.
    __shared__ float xs[D_DIM];
    {
        const float4* xrow = reinterpret_cast<const float4*>(x + (size_t)b * D_DIM);
        float4* xs4 = reinterpret_cast<float4*>(xs);
        xs4[tid] = xrow[tid];   // 256 threads x 16B = 4 KB
    }
    __syncthreads();

    const int gi = g[b] % G_DIM;
    const float* __restrict__ Tm = T + (size_t)gi * D_DIM * D_DIM + col;

    float acc = 0.0f;
    #pragma unroll 8
    for (int d = 0; d < D_DIM; ++d) {
        // lanes contiguous in `col` -> coalesced 256B/wave per load
        acc = fmaf(xs[d], Tm[(size_t)d * D_DIM], acc);
    }

    out[(size_t)b * D_DIM + col] = acc;
}

extern "C" void kernel_launch(void* const* d_in, const int* in_sizes, int n_in,
                              void* d_out, int out_size, void* d_ws, size_t ws_size,
                              hipStream_t stream)
{
    const float* x = (const float*)d_in[0];
    const int*   g = (const int*)d_in[1];
    const float* T = (const float*)d_in[2];
    float* out = (float*)d_out;

    dim3 grid(B_DIM, D_DIM / COLS_PER_BLOCK);   // 128 x 4 = 512 blocks
    leqfc_matvec<<<grid, THREADS, 0, stream>>>(x, g, T, out);
}

// Round 2
// 33.405 us; speedup vs baseline: 2.0353x; 2.0353x over previous
//
#include <hip/hip_runtime.h>

// out[b, e] = sum_d x[b, d] * T[g[b] % G, d, e]
// B=128, D=1024, G=40, all float32.
//
// Strategy: group samples by gi = g[b] % 40 so each matrix column chunk is
// loaded once and reused for up to 8 samples (avg group size 3.2). Split D
// into 16 chunks for occupancy; partial sums land in d_ws and a reduce
// kernel folds them (deterministic: every partial written exactly once).

#define B_DIM   128
#define D_DIM   1024
#define G_DIM   40
#define DSPLIT  16
#define DCHUNK  (D_DIM / DSPLIT)   // 64 rows of T per block
#define SMAX    8                  // samples processed per pass
#define THREADS 256                // 256 threads * float4 = 1024 columns

// USE_ATOMIC=0: write partials to part[dc][b][e]. USE_ATOMIC=1: atomicAdd into out.
template <int USE_ATOMIC>
__global__ __launch_bounds__(THREADS) void leqfc_grouped(
    const float* __restrict__ x,
    const int* __restrict__ g,
    const float* __restrict__ T,
    float* __restrict__ part,
    float* __restrict__ out)
{
    const int gi  = blockIdx.x;        // group 0..39
    const int dc  = blockIdx.y;        // d-chunk 0..15
    const int dbase = dc * DCHUNK;
    const int tid = threadIdx.x;

    __shared__ int   mem[B_DIM];
    __shared__ int   cnt;
    __shared__ float xs[SMAX][DCHUNK]; // 2 KB

    if (tid == 0) cnt = 0;
    __syncthreads();
    if (tid < B_DIM) {
        if ((g[tid] % G_DIM) == gi) {
            int i = atomicAdd(&cnt, 1);
            mem[i] = tid;
        }
    }
    __syncthreads();
    const int m = cnt;

    const float* __restrict__ Tg = T + (size_t)gi * D_DIM * D_DIM;
    // float4 view of this block's T rows; thread owns columns [tid*4, tid*4+3]
    const float4* __restrict__ Trow =
        reinterpret_cast<const float4*>(Tg + (size_t)dbase * D_DIM) + tid;

    for (int s0 = 0; s0 < m; s0 += SMAX) {
        const int mc = min(SMAX, m - s0);

        __syncthreads(); // xs consumers from previous pass done
        #pragma unroll
        for (int k = 0; k < (SMAX * DCHUNK) / THREADS; ++k) {
            int idx = tid + k * THREADS;
            int j  = idx >> 6;       // / DCHUNK
            int dd = idx & (DCHUNK - 1);
            xs[j][dd] = (j < mc)
                ? x[(size_t)mem[s0 + j] * D_DIM + dbase + dd]
                : 0.0f;
        }
        __syncthreads();

        float4 acc[SMAX];
        #pragma unroll
        for (int j = 0; j < SMAX; ++j) acc[j] = make_float4(0.f, 0.f, 0.f, 0.f);

        #pragma unroll 4
        for (int dd = 0; dd < DCHUNK; ++dd) {
            float4 t = Trow[(size_t)dd * (D_DIM / 4)];
            #pragma unroll
            for (int j = 0; j < SMAX; ++j) {
                float xv = xs[j][dd];   // LDS broadcast
                acc[j].x = fmaf(xv, t.x, acc[j].x);
                acc[j].y = fmaf(xv, t.y, acc[j].y);
                acc[j].z = fmaf(xv, t.z, acc[j].z);
                acc[j].w = fmaf(xv, t.w, acc[j].w);
            }
        }

        #pragma unroll
        for (int j = 0; j < SMAX; ++j) {   // static index; predicated store
            if (j < mc) {
                const int b = mem[s0 + j];
                if (USE_ATOMIC) {
                    float* o = out + (size_t)b * D_DIM + tid * 4;
                    atomicAdd(o + 0, acc[j].x);
                    atomicAdd(o + 1, acc[j].y);
                    atomicAdd(o + 2, acc[j].z);
                    atomicAdd(o + 3, acc[j].w);
                } else {
                    float4* o = reinterpret_cast<float4*>(
                        part + ((size_t)dc * B_DIM + b) * D_DIM) + tid;
                    *o = acc[j];
                }
            }
        }
    }
}

__global__ __launch_bounds__(256) void leqfc_reduce(
    const float* __restrict__ part, float* __restrict__ out)
{
    const int idx = blockIdx.x * 256 + threadIdx.x;  // 0 .. B*D-1
    float s = 0.f;
    #pragma unroll
    for (int p = 0; p < DSPLIT; ++p)
        s += part[(size_t)p * B_DIM * D_DIM + idx];
    out[idx] = s;
}

__global__ __launch_bounds__(256) void leqfc_zero(float* __restrict__ out)
{
    out[blockIdx.x * 256 + threadIdx.x] = 0.f;
}

extern "C" void kernel_launch(void* const* d_in, const int* in_sizes, int n_in,
                              void* d_out, int out_size, void* d_ws, size_t ws_size,
                              hipStream_t stream)
{
    const float* x = (const float*)d_in[0];
    const int*   g = (const int*)d_in[1];
    const float* T = (const float*)d_in[2];
    float* out = (float*)d_out;

    const size_t need = (size_t)DSPLIT * B_DIM * D_DIM * sizeof(float); // 8 MB
    dim3 grid(G_DIM, DSPLIT);

    if (ws_size >= need) {
        float* part = (float*)d_ws;
        leqfc_grouped<0><<<grid, THREADS, 0, stream>>>(x, g, T, part, nullptr);
        leqfc_reduce<<<(B_DIM * D_DIM) / 256, 256, 0, stream>>>(part, out);
    } else {
        leqfc_zero<<<(B_DIM * D_DIM) / 256, 256, 0, stream>>>(out);
        leqfc_grouped<1><<<grid, THREADS, 0, stream>>>(x, g, T, nullptr, out);
    }
}